// Round 4
// baseline (42.614 us; speedup 1.0000x reference)
//
#include <hip/hip_runtime.h>

typedef short bf16x8 __attribute__((ext_vector_type(8)));
typedef float f32x4  __attribute__((ext_vector_type(4)));

static constexpr int KH = 15, KW = 15;
static constexpr int HI = 4096, WI = 4096;
static constexpr int HO = HI - KH + 1, WO = WI - KW + 1;   // 4082 x 4082
static constexpr int TM = 64, TN = 128;                    // output tile
static constexpr int NT = 4;                               // tiles marched per block (vertical)
static constexpr int LR   = TM + KH - 1;                   // 78 staged rows
static constexpr int LC   = TN + 16;                       // 144 staged bf16 cols
static constexpr int LSTR = 152;                           // 304 B/row: 16B-aligned, 2-way max alias
static constexpr int IPR   = LC / 4;                       // 36 float4 items per row
static constexpr int ITEMS = LR * IPR;                     // 2808 items per tile
static constexpr int SITER = (ITEMS + 511) / 512;          // 6 staging iterations/thread

__device__ __forceinline__ unsigned int f2bf(float f) {
  unsigned int u = __builtin_bit_cast(unsigned int, f);
  return (u + 0x7FFFu + ((u >> 16) & 1u)) >> 16;
}

__device__ __forceinline__ unsigned int cvt_pk_bf16(float lo, float hi) {
  unsigned int r;
  asm("v_cvt_pk_bf16_f32 %0, %1, %2" : "=v"(r) : "v"(lo), "v"(hi));
  return r;   // low16 = bf16(lo), high16 = bf16(hi)
}

__device__ __forceinline__ float4 load_item(const float* __restrict__ x,
                                            int row0, int col0, int it) {
  float4 v = make_float4(0.f, 0.f, 0.f, 0.f);
  if (it < ITEMS) {
    const int r  = it / IPR;
    const int c4 = (it - r * IPR) * 4;
    const int gr = row0 + r;
    const int gc = col0 + c4;
    if (gr < HI) {
      const float* p = &x[(long)gr * WI + gc];
      if (gc + 3 < WI) {
        v = *(const float4*)p;
      } else {
        if (gc + 0 < WI) v.x = p[0];
        if (gc + 1 < WI) v.y = p[1];
        if (gc + 2 < WI) v.z = p[2];
        if (gc + 3 < WI) v.w = p[3];
      }
    }
  }
  return v;
}

__device__ __forceinline__ void write_item(unsigned short* sx, int it, float4 v) {
  if (it < ITEMS) {
    const int r  = it / IPR;
    const int c4 = (it - r * IPR) * 4;
    uint2 d = make_uint2(cvt_pk_bf16(v.x, v.y), cvt_pk_bf16(v.z, v.w));
    *(uint2*)&sx[r * LSTR + c4] = d;
  }
}

__global__ __launch_bounds__(512, 4)
void conv2d_mfma3(const float* __restrict__ x, const float* __restrict__ w,
                  const float* __restrict__ bias, float* __restrict__ out) {
  __shared__ unsigned short sx[2][LR * LSTR];     // 2 x 23,712 B input tiles
  __shared__ unsigned short btab[15 * 64 * 8];    // 15,360 B banded B-fragments

  const int tid   = threadIdx.x;
  const int col0  = blockIdx.x * TN;
  const int srow0 = blockIdx.y * (NT * TM);

  // ---- issue tile-0 staging loads early ----
  float4 v[SITER];
  #pragma unroll
  for (int k = 0; k < SITER; ++k) v[k] = load_item(x, srow0, col0, tid + 512 * k);

  // ---- build banded weight fragments from global w (L2 broadcast):
  //      B_kh[p][j] = w[kh, p-j] if 0 <= p-j < 15 else 0
  for (int i = tid; i < 15 * 64; i += 512) {
    const int kh = i >> 6;
    const int l  = i & 63;
    const int j  = l & 15;
    const int p0 = (l >> 4) * 8;
    unsigned int d[4];
    #pragma unroll
    for (int t2 = 0; t2 < 4; ++t2) {
      const int idx0 = p0 + 2 * t2 - j;
      const int idx1 = idx0 + 1;
      const unsigned int b0 = (idx0 >= 0 && idx0 < KW) ? f2bf(w[kh * KW + idx0]) : 0u;
      const unsigned int b1 = (idx1 >= 0 && idx1 < KW) ? f2bf(w[kh * KW + idx1]) : 0u;
      d[t2] = b0 | (b1 << 16);
    }
    *(uint4*)&btab[i * 8] = make_uint4(d[0], d[1], d[2], d[3]);
  }

  // ---- convert + write tile 0 ----
  #pragma unroll
  for (int k = 0; k < SITER; ++k) write_item(&sx[0][0], tid + 512 * k, v[k]);

  const float bs = bias[0];
  __syncthreads();

  // ---- per-wave setup ----
  const int lane = tid & 63;
  const int wv   = tid >> 6;                       // wave -> output cols wv*16..+15
  const int arow = lane & 15;
  const int acol = wv * 16 + (lane >> 4) * 8;

  bf16x8 bfrag[15];
  #pragma unroll
  for (int kh = 0; kh < 15; ++kh)
    bfrag[kh] = *(const bf16x8*)&btab[(kh * 64 + lane) * 8];

  int cur = 0;
  for (int t = 0; t < NT; ++t) {
    const int row0 = srow0 + t * TM;

    // issue next-tile loads (latency hides under the MFMA phase)
    if (t + 1 < NT) {
      #pragma unroll
      for (int k = 0; k < SITER; ++k)
        v[k] = load_item(x, row0 + TM, col0, tid + 512 * k);
    }

    // compute current tile: 60 ds_read_b128 + 60 MFMA per wave
    const unsigned short* abase = &sx[cur][arow * LSTR + acol];
    f32x4 acc[4];
    #pragma unroll
    for (int m = 0; m < 4; ++m) acc[m] = (f32x4){0.f, 0.f, 0.f, 0.f};

    #pragma unroll
    for (int kh = 0; kh < 15; ++kh) {
      #pragma unroll
      for (int m = 0; m < 4; ++m) {
        bf16x8 a = *(const bf16x8*)(abase + (16 * m + kh) * LSTR);
        acc[m] = __builtin_amdgcn_mfma_f32_16x16x32_bf16(a, bfrag[kh], acc[m], 0, 0, 0);
      }
    }

    // store outputs: C/D layout col=lane&15, row=(lane>>4)*4+reg
    const int ocol = col0 + wv * 16 + (lane & 15);
    if (ocol < WO) {
      #pragma unroll
      for (int m = 0; m < 4; ++m) {
        const int orow0 = row0 + 16 * m + (lane >> 4) * 4;
        #pragma unroll
        for (int r = 0; r < 4; ++r) {
          const int orow = orow0 + r;
          if (orow < HO) out[(long)orow * WO + ocol] = acc[m][r] + bs;
        }
      }
    }

    // write next tile into the other buffer (other waves still read buf[cur])
    if (t + 1 < NT) {
      #pragma unroll
      for (int k = 0; k < SITER; ++k)
        write_item(&sx[cur ^ 1][0], tid + 512 * k, v[k]);
    }
    __syncthreads();
    cur ^= 1;
  }
}

extern "C" void kernel_launch(void* const* d_in, const int* in_sizes, int n_in,
                              void* d_out, int out_size, void* d_ws, size_t ws_size,
                              hipStream_t stream) {
  const float* x    = (const float*)d_in[0];
  const float* w    = (const float*)d_in[1];
  const float* bias = (const float*)d_in[2];
  float* out        = (float*)d_out;

  dim3 grid((WO + TN - 1) / TN, HI / (NT * TM));   // 32 x 16 = 512 blocks, 2/CU resident
  conv2d_mfma3<<<grid, dim3(512, 1, 1), 0, stream>>>(x, w, bias, out);
}